// Round 1
// baseline (435.568 us; speedup 1.0000x reference)
//
#include <hip/hip_runtime.h>

#define K_DIM 4096
#define N_DIM 4096
#define M_TOT 8192          // B * M = 2 * 4096
#define INT8_BOUND 127.0f
#define BK 128              // k-bytes per GEMM k-tile
#define NT (K_DIM / BK)     // 32 k-tiles

typedef int v4i  __attribute__((ext_vector_type(4)));
typedef int v16i __attribute__((ext_vector_type(16)));

// async global->LDS, 16B per lane; dest = wave-uniform base + lane*16
#define GLOAD_LDS16(g, l)                                                      \
    __builtin_amdgcn_global_load_lds(                                          \
        (const __attribute__((address_space(1))) void*)(g),                    \
        (__attribute__((address_space(3))) void*)(l), 16, 0, 0)

__device__ __forceinline__ int sat8(float x) {
    return (int)fminf(127.f, fmaxf(-127.f, x));
}

// ---------------------------------------------------------------------------
// Kernel 1: quantize lhs rows. One block (256 thr) per row of K=4096 floats.
// ---------------------------------------------------------------------------
__global__ __launch_bounds__(256) void quant_lhs_kernel(const float* __restrict__ lhs,
                                                        char* __restrict__ q_l,
                                                        float* __restrict__ s_l) {
    __shared__ float red[4];
    const int row = blockIdx.x;
    const int t = threadIdx.x;
    const float4* x4 = (const float4*)(lhs + (size_t)row * K_DIM);

    float4 v[4];
    float amax = 0.f;
#pragma unroll
    for (int c = 0; c < 4; ++c) {
        v[c] = x4[t + c * 256];
        amax = fmaxf(amax, fmaxf(fmaxf(fabsf(v[c].x), fabsf(v[c].y)),
                                 fmaxf(fabsf(v[c].z), fabsf(v[c].w))));
    }
#pragma unroll
    for (int off = 32; off > 0; off >>= 1)
        amax = fmaxf(amax, __shfl_xor(amax, off, 64));
    if ((t & 63) == 0) red[t >> 6] = amax;
    __syncthreads();
    amax = fmaxf(fmaxf(red[0], red[1]), fmaxf(red[2], red[3]));

    const float scale = (amax > 0.f) ? (amax / INT8_BOUND) : 1.0f;
    const float inv = (amax > 0.f) ? (INT8_BOUND / amax) : 1.0f;
    if (t == 0) s_l[row] = scale;

    int* qrow = (int*)(q_l + (size_t)row * K_DIM);
#pragma unroll
    for (int c = 0; c < 4; ++c) {
        int b0 = sat8(rintf(v[c].x * inv));
        int b1 = sat8(rintf(v[c].y * inv));
        int b2 = sat8(rintf(v[c].z * inv));
        int b3 = sat8(rintf(v[c].w * inv));
        qrow[t + c * 256] = (b0 & 0xff) | ((b1 & 0xff) << 8) | ((b2 & 0xff) << 16) | (b3 << 24);
    }
}

// ---------------------------------------------------------------------------
// Kernel 2: per-column absmax of rhs [K x N].
// ---------------------------------------------------------------------------
__global__ __launch_bounds__(256) void rhs_amax_kernel(const float* __restrict__ rhs,
                                                       unsigned* __restrict__ amax_r) {
    const int t = threadIdx.x;
    const int nf = blockIdx.x * 256 + t;       // float4 column group 0..1023
    const int k0 = blockIdx.y * 64;
    const float4* r4 = (const float4*)rhs;
    float4 m = {0.f, 0.f, 0.f, 0.f};
#pragma unroll 8
    for (int k = 0; k < 64; ++k) {
        float4 v = r4[(size_t)(k0 + k) * (N_DIM / 4) + nf];
        m.x = fmaxf(m.x, fabsf(v.x));
        m.y = fmaxf(m.y, fabsf(v.y));
        m.z = fmaxf(m.z, fabsf(v.z));
        m.w = fmaxf(m.w, fabsf(v.w));
    }
    atomicMax(&amax_r[nf * 4 + 0], __float_as_uint(m.x));
    atomicMax(&amax_r[nf * 4 + 1], __float_as_uint(m.y));
    atomicMax(&amax_r[nf * 4 + 2], __float_as_uint(m.z));
    atomicMax(&amax_r[nf * 4 + 3], __float_as_uint(m.w));
}

// ---------------------------------------------------------------------------
// Kernel 3: quantize rhs and transpose to q_rT (int8, [N x K], K contiguous).
// ---------------------------------------------------------------------------
__global__ __launch_bounds__(256) void rhs_quant_kernel(const float* __restrict__ rhs,
                                                        const unsigned* __restrict__ amax_r,
                                                        char* __restrict__ q_rt) {
    __shared__ char tile[64 * 136];   // [n][k], stride 136
    const int t = threadIdx.x;
    const int k0 = blockIdx.x * 128;
    const int n0 = blockIdx.y * 64;
    const int nf = t & 15;            // float4 column group
    const int kb = (t >> 4) * 8;      // contiguous 8-k strip

    float inv[4];
#pragma unroll
    for (int q = 0; q < 4; ++q) {
        float am = __uint_as_float(amax_r[n0 + nf * 4 + q]);
        inv[q] = (am > 0.f) ? (INT8_BOUND / am) : 1.f;
    }
    const float4* r4 = (const float4*)rhs;
    int vals[4][8];
#pragma unroll
    for (int c = 0; c < 8; ++c) {
        float4 v = r4[(size_t)(k0 + kb + c) * (N_DIM / 4) + (n0 >> 2) + nf];
        vals[0][c] = sat8(rintf(v.x * inv[0]));
        vals[1][c] = sat8(rintf(v.y * inv[1]));
        vals[2][c] = sat8(rintf(v.z * inv[2]));
        vals[3][c] = sat8(rintf(v.w * inv[3]));
    }
#pragma unroll
    for (int q = 0; q < 4; ++q) {
        int2 p;
        p.x = (vals[q][0] & 0xff) | ((vals[q][1] & 0xff) << 8) |
              ((vals[q][2] & 0xff) << 16) | (vals[q][3] << 24);
        p.y = (vals[q][4] & 0xff) | ((vals[q][5] & 0xff) << 8) |
              ((vals[q][6] & 0xff) << 16) | (vals[q][7] << 24);
        *(int2*)&tile[(nf * 4 + q) * 136 + kb] = p;
    }
    __syncthreads();
#pragma unroll
    for (int c = 0; c < 2; ++c) {
        const int idx = c * 256 + t;
        const int row = idx >> 3;          // 0..63
        const int ch = (idx & 7) * 16;     // 0..112
        *(v4i*)&q_rt[(size_t)(n0 + row) * K_DIM + k0 + ch] = *(const v4i*)&tile[row * 136 + ch];
    }
}

// ---------------------------------------------------------------------------
// Kernel 4: int8 MFMA GEMM, 256x256 tile, BK=128, 8-wave, 4-phase-per-tile
// pipelined schedule (T2 swizzle + T3/T4 counted vmcnt + T5 setprio).
//
// LDS: [buf(2)][mat(2: A,B)][khalf(2)][16 KiB] = 128 KiB.
// A k-half = 256 rows x 64 B, staged by 2 x global_load_lds rounds (linear
// dest; source pre-swizzled chunk^= (row&3) so ds_read with same XOR is
// bank-balanced: all 32 banks hit exactly 8x per wave b128 read).
//
// Phase p (= K-step ks=32*p) per wave: 6 ds_read_b128 (af[4], bf[2]) ->
// 8 independent MFMAs into acc[4][2]. Stage schedule (1 half/phase):
//   P1: A-kh1(t+1)  P2: B-kh1(t+1)  P3: A-kh0(t+2)  P4: B-kh0(t+2)
// vmcnt(8) at end of P2 and P4 keeps the 4 newest half-tiles in flight,
// never draining to 0 in the main loop. Every slot overwrite is >=2
// barriers after the last read of the previous occupant.
// ---------------------------------------------------------------------------
#define STAGE(dd, mm, kh, kt)                                                  \
    {                                                                          \
        const char* gb = ((mm) ? baseB : baseA) + (kt) * BK + (kh) * 64;       \
        char* lb = &lds[(dd) * 65536 + (mm) * 32768 + (kh) * 16384];           \
        GLOAD_LDS16(gb + goff[0], lb + loff[0]);                               \
        GLOAD_LDS16(gb + goff[1], lb + loff[1]);                               \
    }

#define PHASE(dd, p, STAGE_CODE, VM_CODE)                                      \
    {                                                                          \
        const char* pA = &lds[(dd) * 65536 + ((p) >> 1) * 16384];              \
        const char* pB = pA + 32768;                                           \
        v4i af0 = *(const v4i*)(pA + aoff[0] + cw[p]);                         \
        v4i af1 = *(const v4i*)(pA + aoff[1] + cw[p]);                         \
        v4i af2 = *(const v4i*)(pA + aoff[2] + cw[p]);                         \
        v4i af3 = *(const v4i*)(pA + aoff[3] + cw[p]);                         \
        v4i bf0 = *(const v4i*)(pB + boff[0] + cw[p]);                         \
        v4i bf1 = *(const v4i*)(pB + boff[1] + cw[p]);                         \
        STAGE_CODE;                                                            \
        __builtin_amdgcn_s_barrier();                                          \
        asm volatile("s_waitcnt lgkmcnt(0)" ::: "memory");                     \
        __builtin_amdgcn_sched_barrier(0);                                     \
        __builtin_amdgcn_s_setprio(1);                                         \
        acc[0][0] = __builtin_amdgcn_mfma_i32_32x32x32_i8(af0, bf0, acc[0][0], 0, 0, 0); \
        acc[0][1] = __builtin_amdgcn_mfma_i32_32x32x32_i8(af0, bf1, acc[0][1], 0, 0, 0); \
        acc[1][0] = __builtin_amdgcn_mfma_i32_32x32x32_i8(af1, bf0, acc[1][0], 0, 0, 0); \
        acc[1][1] = __builtin_amdgcn_mfma_i32_32x32x32_i8(af1, bf1, acc[1][1], 0, 0, 0); \
        acc[2][0] = __builtin_amdgcn_mfma_i32_32x32x32_i8(af2, bf0, acc[2][0], 0, 0, 0); \
        acc[2][1] = __builtin_amdgcn_mfma_i32_32x32x32_i8(af2, bf1, acc[2][1], 0, 0, 0); \
        acc[3][0] = __builtin_amdgcn_mfma_i32_32x32x32_i8(af3, bf0, acc[3][0], 0, 0, 0); \
        acc[3][1] = __builtin_amdgcn_mfma_i32_32x32x32_i8(af3, bf1, acc[3][1], 0, 0, 0); \
        __builtin_amdgcn_s_setprio(0);                                         \
        VM_CODE;                                                               \
        __builtin_amdgcn_s_barrier();                                          \
    }

__global__ __launch_bounds__(512, 2) void gemm_i8_kernel(const char* __restrict__ qa,
                                                         const char* __restrict__ qb,
                                                         const float* __restrict__ s_l,
                                                         const unsigned* __restrict__ amax_r,
                                                         float* __restrict__ out) {
    __shared__ char lds[131072];
    const int t = threadIdx.x;
    const int lane = t & 63;
    const int ln31 = lane & 31;
    const int lhi = lane >> 5;
    const int wave = t >> 6;          // 0..7
    const int wm = wave >> 2;         // 0..1 (M half of 256)
    const int wn = wave & 3;          // 0..3 (N quarter of 256)

    // XCD-chunked block swizzle: 512 blocks, 8 XCDs, 64 contiguous wgids/XCD
    const int orig = blockIdx.x;
    const int wgid = (orig & 7) * 64 + (orig >> 3);
    const int bx = wgid & 31;          // 32 M-tiles of 256
    const int by = wgid >> 5;          // 16 N-tiles of 256
    const size_t rowA0 = (size_t)bx * 256;
    const size_t rowB0 = (size_t)by * 256;

    v16i acc[4][2];
#pragma unroll
    for (int i = 0; i < 4; ++i)
#pragma unroll
        for (int j = 0; j < 2; ++j) acc[i][j] = (v16i)(0);

    // staging offsets: round g: slot s = g*512+t; r = s>>2 (row 0..255),
    // cs = s&3 (16B chunk in 64B k-half), source chunk = cs ^ (r&3).
    int goff[2], loff[2];
#pragma unroll
    for (int g = 0; g < 2; ++g) {
        const int s = g * 512 + t;
        const int r = s >> 2;
        const int cg = (s & 3) ^ (r & 3);
        goff[g] = r * K_DIM + cg * 16;
        loff[g] = s * 16;
    }
    const char* baseA = qa + rowA0 * K_DIM;
    const char* baseB = qb + rowB0 * K_DIM;

    // ds_read per-lane constants. Fragment k-window for phase p:
    // k = 32*p + 16*lhi -> local chunk cl = 2*(p&1) + lhi, khalf = p>>1.
    int aoff[4], boff[2], cw[4];
#pragma unroll
    for (int i = 0; i < 4; ++i) aoff[i] = (wm * 128 + i * 32 + ln31) * 64;
#pragma unroll
    for (int j = 0; j < 2; ++j) boff[j] = (wn * 64 + j * 32 + ln31) * 64;
#pragma unroll
    for (int p = 0; p < 4; ++p) cw[p] = (((2 * (p & 1) + lhi) ^ (lane & 3)) << 4);

    // Prologue: kh0(0), kh1(0), kh0(1) -> oldest 4 loads (= kh0 of tile 0)
    // guaranteed resident after vmcnt(8).
    STAGE(0, 0, 0, 0);   // A-kh0 tile0
    STAGE(0, 1, 0, 0);   // B-kh0 tile0
    STAGE(0, 0, 1, 0);   // A-kh1 tile0
    STAGE(0, 1, 1, 0);   // B-kh1 tile0
    STAGE(1, 0, 0, 1);   // A-kh0 tile1
    STAGE(1, 1, 0, 1);   // B-kh0 tile1
    asm volatile("s_waitcnt vmcnt(8)" ::: "memory");
    __builtin_amdgcn_s_barrier();

    for (int kt = 0; kt < NT; ++kt) {
        const int d = kt & 1;
        const int dn = d ^ 1;
        PHASE(d, 0, { if (kt + 1 < NT) STAGE(dn, 0, 1, kt + 1); }, {});
        PHASE(d, 1, { if (kt + 1 < NT) STAGE(dn, 1, 1, kt + 1); },
              { asm volatile("s_waitcnt vmcnt(8)" ::: "memory"); });
        PHASE(d, 2, { if (kt + 2 < NT) STAGE(d, 0, 0, kt + 2); }, {});
        PHASE(d, 3, { if (kt + 2 < NT) STAGE(d, 1, 0, kt + 2); },
              { asm volatile("s_waitcnt vmcnt(8)" ::: "memory"); });
    }

    // Epilogue. 32x32 C/D layout: col=lane&31, row=(reg&3)+8*(reg>>2)+4*(lane>>5)
#pragma unroll
    for (int j = 0; j < 2; ++j) {
        const int col = (int)rowB0 + wn * 64 + j * 32 + ln31;
        const float am = __uint_as_float(amax_r[col]);
        const float sr = (am > 0.f) ? (am / INT8_BOUND) : 1.f;
#pragma unroll
        for (int i = 0; i < 4; ++i) {
            const int rbase = (int)rowA0 + wm * 128 + i * 32 + 4 * lhi;
            const v16i a = acc[i][j];
#pragma unroll
            for (int reg = 0; reg < 16; ++reg) {
                const int row = rbase + (reg & 3) + 8 * (reg >> 2);
                out[(size_t)row * N_DIM + col] = (float)a[reg] * s_l[row] * sr;
            }
        }
    }
}

// ---------------------------------------------------------------------------
extern "C" void kernel_launch(void* const* d_in, const int* in_sizes, int n_in,
                              void* d_out, int out_size, void* d_ws, size_t ws_size,
                              hipStream_t stream) {
    const float* lhs = (const float*)d_in[0];   // [2,4096,4096] fp32
    const float* rhs = (const float*)d_in[1];   // [4096,4096]  fp32
    float* out = (float*)d_out;                 // [2,4096,4096] fp32

    char* ws = (char*)d_ws;
    char* q_l = ws;                                        // 32 MB
    char* q_rt = ws + (size_t)M_TOT * K_DIM;               // 16 MB
    float* s_l = (float*)(q_rt + (size_t)N_DIM * K_DIM);   // 32 KB
    unsigned* amax_r = (unsigned*)(s_l + M_TOT);           // 16 KB

    hipMemsetAsync(amax_r, 0, N_DIM * sizeof(unsigned), stream);

    quant_lhs_kernel<<<M_TOT, 256, 0, stream>>>(lhs, q_l, s_l);
    rhs_amax_kernel<<<dim3(N_DIM / 1024, K_DIM / 64), 256, 0, stream>>>(rhs, amax_r);
    rhs_quant_kernel<<<dim3(K_DIM / 128, N_DIM / 64), 256, 0, stream>>>(rhs, amax_r, q_rt);
    gemm_i8_kernel<<<dim3(M_TOT / 256 * (N_DIM / 256)), 512, 0, stream>>>(q_l, q_rt, s_l, amax_r, out);
}

// Round 2
// 424.402 us; speedup vs baseline: 1.0263x; 1.0263x over previous
//
#include <hip/hip_runtime.h>

#define K_DIM 4096
#define N_DIM 4096
#define M_TOT 8192          // B * M = 2 * 4096
#define INT8_BOUND 127.0f
#define BK 128              // k-bytes per GEMM k-tile
#define NT (K_DIM / BK)     // 32 k-tiles

typedef int v4i  __attribute__((ext_vector_type(4)));
typedef int v16i __attribute__((ext_vector_type(16)));

// async global->LDS, 16B per lane; dest = wave-uniform base + lane*16
#define GLOAD_LDS16(g, l)                                                      \
    __builtin_amdgcn_global_load_lds(                                          \
        (const __attribute__((address_space(1))) void*)(g),                    \
        (__attribute__((address_space(3))) void*)(l), 16, 0, 0)

__device__ __forceinline__ int sat8(float x) {
    return (int)fminf(127.f, fmaxf(-127.f, x));
}

// ---------------------------------------------------------------------------
// Kernel 1: quantize lhs rows. One block (256 thr) per row of K=4096 floats.
// ---------------------------------------------------------------------------
__global__ __launch_bounds__(256) void quant_lhs_kernel(const float* __restrict__ lhs,
                                                        char* __restrict__ q_l,
                                                        float* __restrict__ s_l) {
    __shared__ float red[4];
    const int row = blockIdx.x;
    const int t = threadIdx.x;
    const float4* x4 = (const float4*)(lhs + (size_t)row * K_DIM);

    float4 v[4];
    float amax = 0.f;
#pragma unroll
    for (int c = 0; c < 4; ++c) {
        v[c] = x4[t + c * 256];
        amax = fmaxf(amax, fmaxf(fmaxf(fabsf(v[c].x), fabsf(v[c].y)),
                                 fmaxf(fabsf(v[c].z), fabsf(v[c].w))));
    }
#pragma unroll
    for (int off = 32; off > 0; off >>= 1)
        amax = fmaxf(amax, __shfl_xor(amax, off, 64));
    if ((t & 63) == 0) red[t >> 6] = amax;
    __syncthreads();
    amax = fmaxf(fmaxf(red[0], red[1]), fmaxf(red[2], red[3]));

    const float scale = (amax > 0.f) ? (amax / INT8_BOUND) : 1.0f;
    const float inv = (amax > 0.f) ? (INT8_BOUND / amax) : 1.0f;
    if (t == 0) s_l[row] = scale;

    int* qrow = (int*)(q_l + (size_t)row * K_DIM);
#pragma unroll
    for (int c = 0; c < 4; ++c) {
        int b0 = sat8(rintf(v[c].x * inv));
        int b1 = sat8(rintf(v[c].y * inv));
        int b2 = sat8(rintf(v[c].z * inv));
        int b3 = sat8(rintf(v[c].w * inv));
        qrow[t + c * 256] = (b0 & 0xff) | ((b1 & 0xff) << 8) | ((b2 & 0xff) << 16) | (b3 << 24);
    }
}

// ---------------------------------------------------------------------------
// Kernel 2: per-column absmax of rhs [K x N].
// ---------------------------------------------------------------------------
__global__ __launch_bounds__(256) void rhs_amax_kernel(const float* __restrict__ rhs,
                                                       unsigned* __restrict__ amax_r) {
    const int t = threadIdx.x;
    const int nf = blockIdx.x * 256 + t;       // float4 column group 0..1023
    const int k0 = blockIdx.y * 64;
    const float4* r4 = (const float4*)rhs;
    float4 m = {0.f, 0.f, 0.f, 0.f};
#pragma unroll 8
    for (int k = 0; k < 64; ++k) {
        float4 v = r4[(size_t)(k0 + k) * (N_DIM / 4) + nf];
        m.x = fmaxf(m.x, fabsf(v.x));
        m.y = fmaxf(m.y, fabsf(v.y));
        m.z = fmaxf(m.z, fabsf(v.z));
        m.w = fmaxf(m.w, fabsf(v.w));
    }
    atomicMax(&amax_r[nf * 4 + 0], __float_as_uint(m.x));
    atomicMax(&amax_r[nf * 4 + 1], __float_as_uint(m.y));
    atomicMax(&amax_r[nf * 4 + 2], __float_as_uint(m.z));
    atomicMax(&amax_r[nf * 4 + 3], __float_as_uint(m.w));
}

// ---------------------------------------------------------------------------
// Kernel 3: quantize rhs and transpose to q_rT (int8, [N x K], K contiguous).
// ---------------------------------------------------------------------------
__global__ __launch_bounds__(256) void rhs_quant_kernel(const float* __restrict__ rhs,
                                                        const unsigned* __restrict__ amax_r,
                                                        char* __restrict__ q_rt) {
    __shared__ char tile[64 * 136];   // [n][k], stride 136
    const int t = threadIdx.x;
    const int k0 = blockIdx.x * 128;
    const int n0 = blockIdx.y * 64;
    const int nf = t & 15;            // float4 column group
    const int kb = (t >> 4) * 8;      // contiguous 8-k strip

    float inv[4];
#pragma unroll
    for (int q = 0; q < 4; ++q) {
        float am = __uint_as_float(amax_r[n0 + nf * 4 + q]);
        inv[q] = (am > 0.f) ? (INT8_BOUND / am) : 1.f;
    }
    const float4* r4 = (const float4*)rhs;
    int vals[4][8];
#pragma unroll
    for (int c = 0; c < 8; ++c) {
        float4 v = r4[(size_t)(k0 + kb + c) * (N_DIM / 4) + (n0 >> 2) + nf];
        vals[0][c] = sat8(rintf(v.x * inv[0]));
        vals[1][c] = sat8(rintf(v.y * inv[1]));
        vals[2][c] = sat8(rintf(v.z * inv[2]));
        vals[3][c] = sat8(rintf(v.w * inv[3]));
    }
#pragma unroll
    for (int q = 0; q < 4; ++q) {
        int2 p;
        p.x = (vals[q][0] & 0xff) | ((vals[q][1] & 0xff) << 8) |
              ((vals[q][2] & 0xff) << 16) | (vals[q][3] << 24);
        p.y = (vals[q][4] & 0xff) | ((vals[q][5] & 0xff) << 8) |
              ((vals[q][6] & 0xff) << 16) | (vals[q][7] << 24);
        *(int2*)&tile[(nf * 4 + q) * 136 + kb] = p;
    }
    __syncthreads();
#pragma unroll
    for (int c = 0; c < 2; ++c) {
        const int idx = c * 256 + t;
        const int row = idx >> 3;          // 0..63
        const int ch = (idx & 7) * 16;     // 0..112
        *(v4i*)&q_rt[(size_t)(n0 + row) * K_DIM + k0 + ch] = *(const v4i*)&tile[row * 136 + ch];
    }
}

// ---------------------------------------------------------------------------
// Kernel 4: int8 MFMA GEMM, 256x256 tile, BK=128, 8-wave, 4-phase-per-tile
// pipelined schedule (T2 swizzle + T3/T4 counted vmcnt + T5 setprio).
//
// LDS: [buf(2)][mat(2: A,B)][khalf(2)][16 KiB] = 128 KiB.
//
// Bank swizzle (fixed R1->R2): 64-B rows => quad(row,chunk) = 4*(row&1)+chunk.
// chunk ^= ((row>>1)&3) makes (row&1,(row>>1)&3) enumerate all 8 quads across
// every 8 consecutive lanes -> conflict-free ds_read_b128. (The R1 version
// XORed with (row&3): only 4 quads covered, 2-way each -> 2.25x conflicts.)
//
// Phase p (= K-step ks=32*p) per wave: 6 ds_read_b128 (af[4], bf[2]) ->
// 8 independent MFMAs into acc[4][2]. Stage schedule (1 half/phase):
//   P1: A-kh1(t+1)  P2: B-kh1(t+1)  P3: A-kh0(t+2)  P4: B-kh0(t+2)
// vmcnt(8) at end of P2 and P4 keeps the 4 newest half-tiles in flight,
// never draining to 0 in the main loop. Every slot overwrite is >=2
// barriers after the last read of the previous occupant.
// ---------------------------------------------------------------------------
#define STAGE(dd, mm, kh, kt)                                                  \
    {                                                                          \
        const char* gb = ((mm) ? baseB : baseA) + (kt) * BK + (kh) * 64;       \
        char* lb = &lds[(dd) * 65536 + (mm) * 32768 + (kh) * 16384];           \
        GLOAD_LDS16(gb + goff[0], lb + loff[0]);                               \
        GLOAD_LDS16(gb + goff[1], lb + loff[1]);                               \
    }

#define PHASE(dd, p, STAGE_CODE, VM_CODE)                                      \
    {                                                                          \
        const char* pA = &lds[(dd) * 65536 + ((p) >> 1) * 16384];              \
        const char* pB = pA + 32768;                                           \
        v4i af0 = *(const v4i*)(pA + aoff[0] + cw[p]);                         \
        v4i af1 = *(const v4i*)(pA + aoff[1] + cw[p]);                         \
        v4i af2 = *(const v4i*)(pA + aoff[2] + cw[p]);                         \
        v4i af3 = *(const v4i*)(pA + aoff[3] + cw[p]);                         \
        v4i bf0 = *(const v4i*)(pB + boff[0] + cw[p]);                         \
        v4i bf1 = *(const v4i*)(pB + boff[1] + cw[p]);                         \
        STAGE_CODE;                                                            \
        __builtin_amdgcn_s_barrier();                                          \
        asm volatile("s_waitcnt lgkmcnt(0)" ::: "memory");                     \
        __builtin_amdgcn_sched_barrier(0);                                     \
        __builtin_amdgcn_s_setprio(1);                                         \
        acc[0][0] = __builtin_amdgcn_mfma_i32_32x32x32_i8(af0, bf0, acc[0][0], 0, 0, 0); \
        acc[0][1] = __builtin_amdgcn_mfma_i32_32x32x32_i8(af0, bf1, acc[0][1], 0, 0, 0); \
        acc[1][0] = __builtin_amdgcn_mfma_i32_32x32x32_i8(af1, bf0, acc[1][0], 0, 0, 0); \
        acc[1][1] = __builtin_amdgcn_mfma_i32_32x32x32_i8(af1, bf1, acc[1][1], 0, 0, 0); \
        acc[2][0] = __builtin_amdgcn_mfma_i32_32x32x32_i8(af2, bf0, acc[2][0], 0, 0, 0); \
        acc[2][1] = __builtin_amdgcn_mfma_i32_32x32x32_i8(af2, bf1, acc[2][1], 0, 0, 0); \
        acc[3][0] = __builtin_amdgcn_mfma_i32_32x32x32_i8(af3, bf0, acc[3][0], 0, 0, 0); \
        acc[3][1] = __builtin_amdgcn_mfma_i32_32x32x32_i8(af3, bf1, acc[3][1], 0, 0, 0); \
        __builtin_amdgcn_s_setprio(0);                                         \
        VM_CODE;                                                               \
        __builtin_amdgcn_s_barrier();                                          \
    }

__global__ __launch_bounds__(512, 2) void gemm_i8_kernel(const char* __restrict__ qa,
                                                         const char* __restrict__ qb,
                                                         const float* __restrict__ s_l,
                                                         const unsigned* __restrict__ amax_r,
                                                         float* __restrict__ out) {
    __shared__ char lds[131072];
    const int t = threadIdx.x;
    const int lane = t & 63;
    const int ln31 = lane & 31;
    const int lhi = lane >> 5;
    const int wave = t >> 6;          // 0..7
    const int wm = wave >> 2;         // 0..1 (M half of 256)
    const int wn = wave & 3;          // 0..3 (N quarter of 256)

    // XCD swizzle (fixed R1->R2): XCD x = orig&7 owns the 4-wide bx strip
    // [4x, 4x+4) over all 16 by (A-strip = 4 MB, L2-resident; B partitioned
    // across time). by-major serpentine so the ~32 concurrent blocks per XCD
    // share B panels. R1's mapping replicated all of A on every XCD
    // (8*32 + 16 = 272 MB ~= measured 270 MB FETCH).
    const int orig = blockIdx.x;
    const int x = orig & 7;
    const int idx = orig >> 3;         // 0..63
    const int by = idx >> 2;           // 0..15
    const int bxo = (by & 1) ? (3 - (idx & 3)) : (idx & 3);
    const int bx = x * 4 + bxo;        // 0..31
    const size_t rowA0 = (size_t)bx * 256;
    const size_t rowB0 = (size_t)by * 256;

    v16i acc[4][2];
#pragma unroll
    for (int i = 0; i < 4; ++i)
#pragma unroll
        for (int j = 0; j < 2; ++j) acc[i][j] = (v16i)(0);

    // staging offsets: round g: slot s = g*512+t; r = s>>2 (row 0..255),
    // cs = s&3 (16B chunk in 64B k-half), source chunk = cs ^ ((r>>1)&3).
    int goff[2], loff[2];
#pragma unroll
    for (int g = 0; g < 2; ++g) {
        const int s = g * 512 + t;
        const int r = s >> 2;
        const int cg = (s & 3) ^ ((r >> 1) & 3);
        goff[g] = r * K_DIM + cg * 16;
        loff[g] = s * 16;
    }
    const char* baseA = qa + rowA0 * K_DIM;
    const char* baseB = qb + rowB0 * K_DIM;

    // ds_read per-lane constants. Fragment k-window for phase p:
    // k = 32*p + 16*lhi -> global chunk c = 2*(p&1) + lhi, khalf = p>>1.
    // LDS slot chunk = c ^ ((row>>1)&3); fragment row bases are multiples of
    // 32, so (row>>1)&3 == (ln31>>1)&3.
    int aoff[4], boff[2], cw[4];
#pragma unroll
    for (int i = 0; i < 4; ++i) aoff[i] = (wm * 128 + i * 32 + ln31) * 64;
#pragma unroll
    for (int j = 0; j < 2; ++j) boff[j] = (wn * 64 + j * 32 + ln31) * 64;
#pragma unroll
    for (int p = 0; p < 4; ++p) cw[p] = (((2 * (p & 1) + lhi) ^ ((ln31 >> 1) & 3)) << 4);

    // Prologue: oldest 4 loads (= kh0+kh1 of tile 0 A/B first halves)
    // guaranteed resident after vmcnt(8).
    STAGE(0, 0, 0, 0);   // A-kh0 tile0
    STAGE(0, 1, 0, 0);   // B-kh0 tile0
    STAGE(0, 0, 1, 0);   // A-kh1 tile0
    STAGE(0, 1, 1, 0);   // B-kh1 tile0
    STAGE(1, 0, 0, 1);   // A-kh0 tile1
    STAGE(1, 1, 0, 1);   // B-kh0 tile1
    asm volatile("s_waitcnt vmcnt(8)" ::: "memory");
    __builtin_amdgcn_s_barrier();

    for (int kt = 0; kt < NT; ++kt) {
        const int d = kt & 1;
        const int dn = d ^ 1;
        PHASE(d, 0, { if (kt + 1 < NT) STAGE(dn, 0, 1, kt + 1); }, {});
        PHASE(d, 1, { if (kt + 1 < NT) STAGE(dn, 1, 1, kt + 1); },
              { asm volatile("s_waitcnt vmcnt(8)" ::: "memory"); });
        PHASE(d, 2, { if (kt + 2 < NT) STAGE(d, 0, 0, kt + 2); }, {});
        PHASE(d, 3, { if (kt + 2 < NT) STAGE(d, 1, 0, kt + 2); },
              { asm volatile("s_waitcnt vmcnt(8)" ::: "memory"); });
    }

    // Epilogue. 32x32 C/D layout: col=lane&31, row=(reg&3)+8*(reg>>2)+4*(lane>>5)
#pragma unroll
    for (int j = 0; j < 2; ++j) {
        const int col = (int)rowB0 + wn * 64 + j * 32 + ln31;
        const float am = __uint_as_float(amax_r[col]);
        const float sr = (am > 0.f) ? (am / INT8_BOUND) : 1.f;
#pragma unroll
        for (int i = 0; i < 4; ++i) {
            const int rbase = (int)rowA0 + wm * 128 + i * 32 + 4 * lhi;
            const v16i a = acc[i][j];
#pragma unroll
            for (int reg = 0; reg < 16; ++reg) {
                const int row = rbase + (reg & 3) + 8 * (reg >> 2);
                out[(size_t)row * N_DIM + col] = (float)a[reg] * s_l[row] * sr;
            }
        }
    }
}

// ---------------------------------------------------------------------------
extern "C" void kernel_launch(void* const* d_in, const int* in_sizes, int n_in,
                              void* d_out, int out_size, void* d_ws, size_t ws_size,
                              hipStream_t stream) {
    const float* lhs = (const float*)d_in[0];   // [2,4096,4096] fp32
    const float* rhs = (const float*)d_in[1];   // [4096,4096]  fp32
    float* out = (float*)d_out;                 // [2,4096,4096] fp32

    char* ws = (char*)d_ws;
    char* q_l = ws;                                        // 32 MB
    char* q_rt = ws + (size_t)M_TOT * K_DIM;               // 16 MB
    float* s_l = (float*)(q_rt + (size_t)N_DIM * K_DIM);   // 32 KB
    unsigned* amax_r = (unsigned*)(s_l + M_TOT);           // 16 KB

    hipMemsetAsync(amax_r, 0, N_DIM * sizeof(unsigned), stream);

    quant_lhs_kernel<<<M_TOT, 256, 0, stream>>>(lhs, q_l, s_l);
    rhs_amax_kernel<<<dim3(N_DIM / 1024, K_DIM / 64), 256, 0, stream>>>(rhs, amax_r);
    rhs_quant_kernel<<<dim3(K_DIM / 128, N_DIM / 64), 256, 0, stream>>>(rhs, amax_r, q_rt);
    gemm_i8_kernel<<<dim3(M_TOT / 256 * (N_DIM / 256)), 512, 0, stream>>>(q_l, q_rt, s_l, amax_r, out);
}

// Round 3
// 414.262 us; speedup vs baseline: 1.0514x; 1.0245x over previous
//
#include <hip/hip_runtime.h>

#define K_DIM 4096
#define N_DIM 4096
#define M_TOT 8192          // B * M = 2 * 4096
#define INT8_BOUND 127.0f
#define BK 128              // k-bytes per GEMM k-tile
#define NT (K_DIM / BK)     // 32 k-tiles

typedef int v4i  __attribute__((ext_vector_type(4)));
typedef int v16i __attribute__((ext_vector_type(16)));

// async global->LDS, 16B per lane; dest = wave-uniform base + lane*16
#define GLOAD_LDS16(g, l)                                                      \
    __builtin_amdgcn_global_load_lds(                                          \
        (const __attribute__((address_space(1))) void*)(g),                    \
        (__attribute__((address_space(3))) void*)(l), 16, 0, 0)

__device__ __forceinline__ int sat8(float x) {
    return (int)fminf(127.f, fmaxf(-127.f, x));
}

// ---------------------------------------------------------------------------
// Kernel 1: quantize lhs rows. One block (256 thr) per row of K=4096 floats.
// ---------------------------------------------------------------------------
__global__ __launch_bounds__(256) void quant_lhs_kernel(const float* __restrict__ lhs,
                                                        char* __restrict__ q_l,
                                                        float* __restrict__ s_l) {
    __shared__ float red[4];
    const int row = blockIdx.x;
    const int t = threadIdx.x;
    const float4* x4 = (const float4*)(lhs + (size_t)row * K_DIM);

    float4 v[4];
    float amax = 0.f;
#pragma unroll
    for (int c = 0; c < 4; ++c) {
        v[c] = x4[t + c * 256];
        amax = fmaxf(amax, fmaxf(fmaxf(fabsf(v[c].x), fabsf(v[c].y)),
                                 fmaxf(fabsf(v[c].z), fabsf(v[c].w))));
    }
#pragma unroll
    for (int off = 32; off > 0; off >>= 1)
        amax = fmaxf(amax, __shfl_xor(amax, off, 64));
    if ((t & 63) == 0) red[t >> 6] = amax;
    __syncthreads();
    amax = fmaxf(fmaxf(red[0], red[1]), fmaxf(red[2], red[3]));

    const float scale = (amax > 0.f) ? (amax / INT8_BOUND) : 1.0f;
    const float inv = (amax > 0.f) ? (INT8_BOUND / amax) : 1.0f;
    if (t == 0) s_l[row] = scale;

    int* qrow = (int*)(q_l + (size_t)row * K_DIM);
#pragma unroll
    for (int c = 0; c < 4; ++c) {
        int b0 = sat8(rintf(v[c].x * inv));
        int b1 = sat8(rintf(v[c].y * inv));
        int b2 = sat8(rintf(v[c].z * inv));
        int b3 = sat8(rintf(v[c].w * inv));
        qrow[t + c * 256] = (b0 & 0xff) | ((b1 & 0xff) << 8) | ((b2 & 0xff) << 16) | (b3 << 24);
    }
}

// ---------------------------------------------------------------------------
// Kernel 2: per-column absmax of rhs [K x N].
// ---------------------------------------------------------------------------
__global__ __launch_bounds__(256) void rhs_amax_kernel(const float* __restrict__ rhs,
                                                       unsigned* __restrict__ amax_r) {
    const int t = threadIdx.x;
    const int nf = blockIdx.x * 256 + t;       // float4 column group 0..1023
    const int k0 = blockIdx.y * 64;
    const float4* r4 = (const float4*)rhs;
    float4 m = {0.f, 0.f, 0.f, 0.f};
#pragma unroll 8
    for (int k = 0; k < 64; ++k) {
        float4 v = r4[(size_t)(k0 + k) * (N_DIM / 4) + nf];
        m.x = fmaxf(m.x, fabsf(v.x));
        m.y = fmaxf(m.y, fabsf(v.y));
        m.z = fmaxf(m.z, fabsf(v.z));
        m.w = fmaxf(m.w, fabsf(v.w));
    }
    atomicMax(&amax_r[nf * 4 + 0], __float_as_uint(m.x));
    atomicMax(&amax_r[nf * 4 + 1], __float_as_uint(m.y));
    atomicMax(&amax_r[nf * 4 + 2], __float_as_uint(m.z));
    atomicMax(&amax_r[nf * 4 + 3], __float_as_uint(m.w));
}

// ---------------------------------------------------------------------------
// Kernel 3: quantize rhs and transpose to q_rT (int8, [N x K], K contiguous).
// ---------------------------------------------------------------------------
__global__ __launch_bounds__(256) void rhs_quant_kernel(const float* __restrict__ rhs,
                                                        const unsigned* __restrict__ amax_r,
                                                        char* __restrict__ q_rt) {
    __shared__ char tile[64 * 136];   // [n][k], stride 136
    const int t = threadIdx.x;
    const int k0 = blockIdx.x * 128;
    const int n0 = blockIdx.y * 64;
    const int nf = t & 15;            // float4 column group
    const int kb = (t >> 4) * 8;      // contiguous 8-k strip

    float inv[4];
#pragma unroll
    for (int q = 0; q < 4; ++q) {
        float am = __uint_as_float(amax_r[n0 + nf * 4 + q]);
        inv[q] = (am > 0.f) ? (INT8_BOUND / am) : 1.f;
    }
    const float4* r4 = (const float4*)rhs;
    int vals[4][8];
#pragma unroll
    for (int c = 0; c < 8; ++c) {
        float4 v = r4[(size_t)(k0 + kb + c) * (N_DIM / 4) + (n0 >> 2) + nf];
        vals[0][c] = sat8(rintf(v.x * inv[0]));
        vals[1][c] = sat8(rintf(v.y * inv[1]));
        vals[2][c] = sat8(rintf(v.z * inv[2]));
        vals[3][c] = sat8(rintf(v.w * inv[3]));
    }
#pragma unroll
    for (int q = 0; q < 4; ++q) {
        int2 p;
        p.x = (vals[q][0] & 0xff) | ((vals[q][1] & 0xff) << 8) |
              ((vals[q][2] & 0xff) << 16) | (vals[q][3] << 24);
        p.y = (vals[q][4] & 0xff) | ((vals[q][5] & 0xff) << 8) |
              ((vals[q][6] & 0xff) << 16) | (vals[q][7] << 24);
        *(int2*)&tile[(nf * 4 + q) * 136 + kb] = p;
    }
    __syncthreads();
#pragma unroll
    for (int c = 0; c < 2; ++c) {
        const int idx = c * 256 + t;
        const int row = idx >> 3;          // 0..63
        const int ch = (idx & 7) * 16;     // 0..112
        *(v4i*)&q_rt[(size_t)(n0 + row) * K_DIM + k0 + ch] = *(const v4i*)&tile[row * 136 + ch];
    }
}

// ---------------------------------------------------------------------------
// Kernel 4: int8 MFMA GEMM, 256x256 tile, BK=128, 4 waves (256 thr),
// per-wave 128x128 output = acc[4][4] of 32x32 tiles.
//
// WHY acc 4x4: the GEMM is LDS-BW-bound. reads/MFMA for an m x n acc grid is
// (m+n)/(m*n): 4x2 = 0.75 (R2: LDS 80us vs MFMA 62us -> 40% util); 4x4 = 0.5
// (LDS ~47us < MFMA 62us -> MFMA-bound). Cost: 256 acc regs -> 1 wave/SIMD;
// covered by intra-wave run-ahead (32 queued MFMAs = ~1170cy drain per phase
// hides next phase's ds_read wait and the per-tile vmcnt(0)).
//
// LDS: [buf(2)][mat(2)] x 32 KiB (256 rows x 128 B) = 128 KiB, double-buffered.
// Swizzle: 128-B rows => quad = chunk&7 (row-invariant). Stage source chunk
// cg = cs ^ (r&7); read lds-chunk = c ^ (row&7) -> 8 consecutive lanes cover
// all 8 quads (uniform).
//
// Per k-tile (2 phases, ONE barrier each):
//  P0: issue STAGE(t+1 -> dn) [16 gload_lds]; 16 ds_read (kh0);
//      barrier; 32 MFMA (ks 0,1).
//  P1: 16 ds_read (kh1); vmcnt(0) [t+1 staged] + lgkmcnt(0) [kh1 reads done
//      BEFORE barrier so next P0's stage can't overwrite them]; barrier;
//      32 MFMA (ks 2,3).
// Hazards: stage(t+1->dn) issues after P1(t-1)'s lgkm+barrier (dn readers
// drained); readers of dn start after P1(t)'s vmcnt(0)+barrier (writes landed).
// ---------------------------------------------------------------------------
#define STAGE(dd, kt)                                                          \
    {                                                                          \
        const char* ga = baseA + (kt) * BK;                                    \
        const char* gb = baseB + (kt) * BK;                                    \
        char* la = &lds[(dd) * 65536];                                         \
        char* lb = la + 32768;                                                 \
        _Pragma("unroll")                                                      \
        for (int g = 0; g < 8; ++g) GLOAD_LDS16(ga + goff[g], la + loff[g]);   \
        _Pragma("unroll")                                                      \
        for (int g = 0; g < 8; ++g) GLOAD_LDS16(gb + goff[g], lb + loff[g]);   \
    }

#define PH(dd, h, PRE)                                                         \
    {                                                                          \
        const char* pa = &lds[(dd) * 65536];                                   \
        const char* pb = pa + 32768;                                           \
        v4i af[4][2], bf[4][2];                                                \
        _Pragma("unroll")                                                      \
        for (int s = 0; s < 2; ++s) {                                          \
            _Pragma("unroll")                                                  \
            for (int i = 0; i < 4; ++i)                                        \
                af[i][s] = *(const v4i*)(pa + aoff[i] + cw[2 * (h) + s]);      \
            _Pragma("unroll")                                                  \
            for (int j = 0; j < 4; ++j)                                        \
                bf[j][s] = *(const v4i*)(pb + boff[j] + cw[2 * (h) + s]);      \
        }                                                                      \
        PRE;                                                                   \
        __builtin_amdgcn_s_barrier();                                          \
        _Pragma("unroll")                                                      \
        for (int s = 0; s < 2; ++s)                                            \
            _Pragma("unroll")                                                  \
            for (int i = 0; i < 4; ++i)                                        \
                _Pragma("unroll")                                              \
                for (int j = 0; j < 4; ++j)                                    \
                    acc[i][j] = __builtin_amdgcn_mfma_i32_32x32x32_i8(         \
                        af[i][s], bf[j][s], acc[i][j], 0, 0, 0);               \
    }

__global__ __launch_bounds__(256, 1) void gemm_i8_kernel(const char* __restrict__ qa,
                                                         const char* __restrict__ qb,
                                                         const float* __restrict__ s_l,
                                                         const unsigned* __restrict__ amax_r,
                                                         float* __restrict__ out) {
    __shared__ char lds[131072];
    const int t = threadIdx.x;
    const int lane = t & 63;
    const int ln31 = lane & 31;
    const int lhi = lane >> 5;
    const int wave = t >> 6;          // 0..3
    const int wm = wave >> 1;         // 0..1 (M half)
    const int wn = wave & 1;          // 0..1 (N half)

    // XCD serpentine: XCD x owns bx strip [4x,4x+4) over all by (A-strip 4MB,
    // L2-resident); by-major serpentine for B-panel sharing in time.
    const int orig = blockIdx.x;
    const int x = orig & 7;
    const int idx = orig >> 3;         // 0..63
    const int by = idx >> 2;           // 0..15
    const int bxo = (by & 1) ? (3 - (idx & 3)) : (idx & 3);
    const int bx = x * 4 + bxo;        // 0..31
    const size_t rowA0 = (size_t)bx * 256;
    const size_t rowB0 = (size_t)by * 256;

    v16i acc[4][4];
#pragma unroll
    for (int i = 0; i < 4; ++i)
#pragma unroll
        for (int j = 0; j < 4; ++j) acc[i][j] = (v16i)(0);

    // staging: slot s = g*256+t; r = s>>3 (row 0..255), cs = s&7 (16B chunk
    // in 128B row), source chunk cg = cs ^ (r&7) -> linear LDS dest, swizzled
    // global source (guide rule #21: both-sides-or-neither).
    int goff[8], loff[8];
#pragma unroll
    for (int g = 0; g < 8; ++g) {
        const int s = g * 256 + t;
        const int r = s >> 3;
        const int cg = (s & 7) ^ (r & 7);
        goff[g] = r * K_DIM + cg * 16;
        loff[g] = s * 16;
    }
    const char* baseA = qa + rowA0 * K_DIM;
    const char* baseB = qb + rowB0 * K_DIM;

    // read offsets: fragment row = base + ln31 (rows of 128 B), chunk for
    // kstep ks: c = 2*ks + lhi, lds chunk = c ^ (row&7), row&7 == ln31&7.
    int aoff[4], boff[4], cw[4];
#pragma unroll
    for (int i = 0; i < 4; ++i) aoff[i] = (wm * 128 + i * 32 + ln31) * BK;
#pragma unroll
    for (int j = 0; j < 4; ++j) boff[j] = (wn * 128 + j * 32 + ln31) * BK;
#pragma unroll
    for (int ks = 0; ks < 4; ++ks) cw[ks] = (((2 * ks + lhi) ^ (ln31 & 7)) << 4);

    // Prologue: stage tile 0, drain, barrier.
    STAGE(0, 0);
    asm volatile("s_waitcnt vmcnt(0)" ::: "memory");
    __builtin_amdgcn_s_barrier();

    for (int kt = 0; kt < NT; ++kt) {
        const int d = kt & 1;
        if (kt + 1 < NT) STAGE(d ^ 1, kt + 1);
        PH(d, 0, {});
        PH(d, 1, {
            asm volatile("s_waitcnt vmcnt(0) lgkmcnt(0)" ::: "memory");
            __builtin_amdgcn_sched_barrier(0);
        });
    }

    // Epilogue. 32x32 C/D layout: col=lane&31, row=(reg&3)+8*(reg>>2)+4*(lane>>5)
    float sr[4];
#pragma unroll
    for (int j = 0; j < 4; ++j) {
        const float am = __uint_as_float(amax_r[(int)rowB0 + wn * 128 + j * 32 + ln31]);
        sr[j] = (am > 0.f) ? (am / INT8_BOUND) : 1.f;
    }
#pragma unroll
    for (int i = 0; i < 4; ++i) {
        const int rbase = (int)rowA0 + wm * 128 + i * 32 + 4 * lhi;
        float sl[16];
#pragma unroll
        for (int reg = 0; reg < 16; ++reg)
            sl[reg] = s_l[rbase + (reg & 3) + 8 * (reg >> 2)];
#pragma unroll
        for (int j = 0; j < 4; ++j) {
            const int col = (int)rowB0 + wn * 128 + j * 32 + ln31;
            const v16i a = acc[i][j];
#pragma unroll
            for (int reg = 0; reg < 16; ++reg) {
                const int row = rbase + (reg & 3) + 8 * (reg >> 2);
                out[(size_t)row * N_DIM + col] = (float)a[reg] * sl[reg] * sr[j];
            }
        }
    }
}

// ---------------------------------------------------------------------------
extern "C" void kernel_launch(void* const* d_in, const int* in_sizes, int n_in,
                              void* d_out, int out_size, void* d_ws, size_t ws_size,
                              hipStream_t stream) {
    const float* lhs = (const float*)d_in[0];   // [2,4096,4096] fp32
    const float* rhs = (const float*)d_in[1];   // [4096,4096]  fp32
    float* out = (float*)d_out;                 // [2,4096,4096] fp32

    char* ws = (char*)d_ws;
    char* q_l = ws;                                        // 32 MB
    char* q_rt = ws + (size_t)M_TOT * K_DIM;               // 16 MB
    float* s_l = (float*)(q_rt + (size_t)N_DIM * K_DIM);   // 32 KB
    unsigned* amax_r = (unsigned*)(s_l + M_TOT);           // 16 KB

    hipMemsetAsync(amax_r, 0, N_DIM * sizeof(unsigned), stream);

    quant_lhs_kernel<<<M_TOT, 256, 0, stream>>>(lhs, q_l, s_l);
    rhs_amax_kernel<<<dim3(N_DIM / 1024, K_DIM / 64), 256, 0, stream>>>(rhs, amax_r);
    rhs_quant_kernel<<<dim3(K_DIM / 128, N_DIM / 64), 256, 0, stream>>>(rhs, amax_r, q_rt);
    gemm_i8_kernel<<<dim3((M_TOT / 256) * (N_DIM / 256)), 256, 0, stream>>>(q_l, q_rt, s_l, amax_r, out);
}